// Round 7
// baseline (854.077 us; speedup 1.0000x reference)
//
#include <hip/hip_runtime.h>

// y[b,s,f] = init[b] + FACTOR * cumsum_s(x)[b,s,f]
// B=1024, S=4096, F=11, fp32. Memory-bound.
//
// Single-pass chained scan with decoupled lookback (rocPRIM-style):
//  - 8192 blocks, one 512-step chunk each. Block gets a TICKET via atomicAdd;
//    ticket -> (row b = tk/8, chunk c = tk&7). Predecessor chunks of a ticket
//    always hold LOWER tickets => already started => no deadlock, no
//    dispatch-order assumption (G16-safe).
//  - Stage chunk via global_load_lds -> float2 LDS transpose (bank stride 22,
//    2-way = free) -> DPP wave scan (pure VALU) -> publish 11-float block
//    aggregate (device-scope atomic stores, drained by syncthreads) +
//    release flag -> spin-acquire <=7 predecessor flags, sum aggregates ->
//    epilogue -> coalesced float4 store.
//  - x read ONCE, y written once. Flags+counter zeroed by a 33 KB
//    hipMemsetAsync at graph level (re-runs every replay).

#define BATCH    1024
#define SEQ      4096
#define FEAT     11
#define FACTOR   (-1.0f)

#define NTHREADS 256
#define TS       512                     // timesteps per chunk
#define NC       (SEQ / TS)              // 8 chunks per row
#define NBLK     (BATCH * NC)            // 8192 blocks
#define TILE_F4  (TS * FEAT / 4)         // 1408 float4 per chunk
#define VLMAX    6                       // ceil(1408/256)
#define NWAVE    (NTHREADS / 64)

// d_ws layout (bytes):
//   [0]                  uint  counter
//   [256 .. 33024)       uint  flags[NBLK]
//   [33024 .. 393472)    float aggs[NBLK][FEAT]
#define WS_FLAGS_OFF  256
#define WS_AGGS_OFF   33024
#define WS_ZERO_BYTES 33024

template <int CTRL, int RM, int BM, bool BC>
__device__ __forceinline__ float dpp_src(float v) {
    int r = __builtin_amdgcn_update_dpp(0, __float_as_int(v), CTRL, RM, BM, BC);
    return __int_as_float(r);
}

// 64-lane inclusive add-scan, pure VALU (verified R3-R5).
__device__ __forceinline__ float wave_iscan(float x) {
    x += dpp_src<0x111, 0xf, 0xf, true >(x);  // row_shr:1
    x += dpp_src<0x112, 0xf, 0xf, true >(x);  // row_shr:2
    x += dpp_src<0x114, 0xf, 0xf, true >(x);  // row_shr:4
    x += dpp_src<0x118, 0xf, 0xf, true >(x);  // row_shr:8
    x += dpp_src<0x142, 0xa, 0xf, false>(x);  // row_bcast:15
    x += dpp_src<0x143, 0xc, 0xf, false>(x);  // row_bcast:31
    return x;
}

__device__ __forceinline__ void gload_lds16(const float4* g, float4* l) {
    __builtin_amdgcn_global_load_lds(
        (const __attribute__((address_space(1))) void*)g,
        (__attribute__((address_space(3))) void*)l, 16, 0, 0);
}

__global__ __launch_bounds__(NTHREADS, 6)
void chained_scan_kernel(const float* __restrict__ x,
                         const float* __restrict__ init_state,
                         float* __restrict__ y,
                         unsigned* __restrict__ counter,
                         unsigned* __restrict__ flags,
                         float* __restrict__ aggs) {
    __shared__ float4    tile[TILE_F4];       // 22,528 B
    __shared__ float     waveTot[NWAVE][FEAT];
    __shared__ float     offsh[FEAT];
    __shared__ unsigned  ticket_sh;

    const int t    = threadIdx.x;
    const int lane = t & 63;
    const int wav  = t >> 6;

    if (t == 0) ticket_sh = atomicAdd(counter, 1u);
    __syncthreads();
    const unsigned tk = ticket_sh;
    const int b = (int)(tk >> 3);             // row
    const int c = (int)(tk & (NC - 1));       // chunk within row

    const float4* xg = (const float4*)x + (size_t)tk * TILE_F4;
    float4*       yg = (float4*)y + (size_t)tk * TILE_F4;
    const float init_v = init_state[b];

    // ---- stage chunk to LDS ----
#pragma unroll
    for (int i = 0; i < VLMAX; ++i) {
        int idx = t + NTHREADS * i;
        if (idx < TILE_F4) gload_lds16(xg + idx, &tile[idx]);
    }
    __syncthreads();

    // ---- transpose read (float2 11t+m: stride 22 words, 2-way banks = free)
    const float2* lds2 = (const float2*)tile;
    float L[2 * FEAT];
#pragma unroll
    for (int m = 0; m < FEAT; ++m) {
        float2 q = lds2[FEAT * t + m];
        L[2 * m]     = q.x;
        L[2 * m + 1] = q.y;
    }
    // local prefix over own 2 steps + wave scan of totals
    float inc[FEAT];
#pragma unroll
    for (int f = 0; f < FEAT; ++f) {
        L[FEAT + f] += L[f];
        inc[f] = wave_iscan(L[FEAT + f]);
    }
    if (lane == 63) {
#pragma unroll
        for (int f = 0; f < FEAT; ++f) waveTot[wav][f] = inc[f];
    }
    __syncthreads();

    // ---- publish block aggregate (device scope) ----
    if (wav == 0 && lane < FEAT) {
        float agg = waveTot[0][lane] + waveTot[1][lane]
                  + waveTot[2][lane] + waveTot[3][lane];
        __hip_atomic_store(&aggs[(size_t)tk * FEAT + lane], agg,
                           __ATOMIC_RELAXED, __HIP_MEMORY_SCOPE_AGENT);
    }
    __syncthreads();   // emits vmcnt(0) drain -> agg stores globally visible
    if (t == 0)
        __hip_atomic_store(&flags[tk], 1u,
                           __ATOMIC_RELEASE, __HIP_MEMORY_SCOPE_AGENT);

    // ---- lookback: sum aggregates of chunks 0..c-1 of this row ----
    if (t < FEAT) {
        float off = 0.0f;
        for (int cc = 0; cc < c; ++cc) {      // uniform across the 11 lanes
            const unsigned pred = (unsigned)(b * NC + cc);
            while (__hip_atomic_load(&flags[pred], __ATOMIC_ACQUIRE,
                                     __HIP_MEMORY_SCOPE_AGENT) == 0u) {
                __builtin_amdgcn_s_sleep(2);
            }
            off += __hip_atomic_load(&aggs[(size_t)pred * FEAT + t],
                                     __ATOMIC_RELAXED, __HIP_MEMORY_SCOPE_AGENT);
        }
        offsh[t] = off;
    }
    __syncthreads();

    // ---- epilogue: global offset + cross-wave + wave-exclusive ----
    float2* ldsw = (float2*)tile;
#pragma unroll
    for (int f = 0; f < FEAT; ++f) {
        float off = offsh[f] + inc[f] - L[FEAT + f];   // exclusive in wave
#pragma unroll
        for (int w = 0; w < NWAVE; ++w)
            if (w < wav) off += waveTot[w][f];
        L[f]        = init_v + FACTOR * (off + L[f]);
        L[FEAT + f] = init_v + FACTOR * (off + L[FEAT + f]);
    }
#pragma unroll
    for (int m = 0; m < FEAT; ++m)            // own slots -> no barrier hazard
        ldsw[FEAT * t + m] = make_float2(L[2 * m], L[2 * m + 1]);
    __syncthreads();

    // ---- coalesced float4 store ----
#pragma unroll
    for (int i = 0; i < VLMAX; ++i) {
        int idx = t + NTHREADS * i;
        if (idx < TILE_F4) yg[idx] = tile[idx];
    }
}

extern "C" void kernel_launch(void* const* d_in, const int* in_sizes, int n_in,
                              void* d_out, int out_size, void* d_ws, size_t ws_size,
                              hipStream_t stream) {
    const float* x    = (const float*)d_in[0];
    const float* init = (const float*)d_in[1];
    float*       y    = (float*)d_out;
    unsigned*    cnt  = (unsigned*)d_ws;
    unsigned*    flg  = (unsigned*)((char*)d_ws + WS_FLAGS_OFF);
    float*       agg  = (float*)((char*)d_ws + WS_AGGS_OFF);

    // zero ticket counter + flags (graph-safe, re-runs every replay)
    hipMemsetAsync(d_ws, 0, WS_ZERO_BYTES, stream);
    chained_scan_kernel<<<dim3(NBLK), dim3(NTHREADS), 0, stream>>>(
        x, init, y, cnt, flg, agg);
}